// Round 8
// baseline (7543.764 us; speedup 1.0000x reference)
//
#include <hip/hip_runtime.h>
#include <math.h>

#define E_ 8192
#define NNODE 1024
#define NCOEF 49
#define MRED 29
#define CC 128
#define C2 256
#define HH 64
#define NHEAD 8
#define ACH 64
#define RESBA 196
#define DDIST_ 512
#define ECHN 128
#define EIN_ 768
#define EXTRA_ 576
#define ALPHACH_ 512
#define RADTOT 4608
#define AMMW 7424   /* 29*256 */
#define MSGW 1856   /* 29*64 */
#define VALW 3712   /* 29*128 */
#define EPB 8

typedef __attribute__((ext_vector_type(8))) short s16x8;
typedef __attribute__((ext_vector_type(4))) float f32x4;

__constant__ int PERM_M_c[MRED] = {0,2,6,11,16,21,26, 3,7,12,17,22,27, 1,5,10,15,20,25, 8,13,18,23,28, 4,9,14,19,24};
__constant__ int RADOFF_c[MRED] = {0,256,512,768,1024,1280,1536,
                                   1792,2048,2304,2560,2816,3072,
                                   1792,2048,2304,2560,2816,3072,
                                   3328,3584,3840,4096,4352,
                                   3328,3584,3840,4096,4352};

__device__ inline float waveSum64(float v){
  #pragma unroll
  for (int d=32; d>0; d>>=1) v += __shfl_xor(v, d, 64);
  return v;
}
__device__ inline float silu_(float x){ return x/(1.f+__expf(-x)); }

// split fp32 -> bf16 hi + bf16 lo (RNE both); a ~= hi + lo, |err| ~ 2^-17 rel
__device__ inline void bfsplit(float x, unsigned short& h, unsigned short& l){
  unsigned u = __float_as_uint(x);
  unsigned hb = (u + 0x7FFFu + ((u>>16)&1u)) >> 16;
  float hf = __uint_as_float(hb << 16);
  float lo = x - hf;
  unsigned ul = __float_as_uint(lo);
  h = (unsigned short)hb;
  l = (unsigned short)((ul + 0x7FFFu + ((ul>>16)&1u)) >> 16);
}

// ---------------- prep: grid tables + proj transpose ----------------
__global__ void k_gridtab(const float* __restrict__ tg, const float* __restrict__ fg,
                          const float* __restrict__ pw,
                          float* __restrict__ tgp, float* __restrict__ fgp, float* __restrict__ pwt)
{
  const int ng = RESBA*MRED, np = 7*128*128;
  int total = 2*ng+np;
  for (int i = blockIdx.x*blockDim.x+threadIdx.x; i < total; i += gridDim.x*blockDim.x){
    int j = i;
    if (j < ng){ int ba=j/MRED,k=j-ba*MRED; tgp[j] = tg[ba*MRED + PERM_M_c[k]]; continue; } j -= ng;
    if (j < ng){ int ba=j/MRED,k=j-ba*MRED; fgp[j] = fg[ba*MRED + PERM_M_c[k]]; continue; } j -= ng;
    { int l = j/16384, r = j-l*16384, v = r>>7, o = r&127; pwt[j] = pw[l*16384 + o*128 + v]; }
  }
}

// SO2 folded weight value: Wbig = [[Wr, Wi], [-Wi, Wr]], idx = k*N + n (row-major KxN)
__device__ inline float so2val(const float* __restrict__ w, int idx, int K0, int h){
  int two_h = 2*h; int k = idx/two_h, jj = idx - k*two_h;
  if (jj < h) return (k<K0) ? w[k*two_h + jj] : -w[(k-K0)*two_h + (h+jj)];
  else        return (k<K0) ? w[k*two_h + jj] :  w[(k-K0)*two_h + (jj-h)];
}
// dst: Bt[n][k] bf16 hi/lo planes from folded SO2 weight (KxN logical)
__global__ void k_wsplit_so2(const float* __restrict__ src, unsigned short* __restrict__ dh,
                             unsigned short* __restrict__ dl, int N, int K, int K0, int h){
  size_t total = (size_t)N*K;
  for (size_t i = (size_t)blockIdx.x*blockDim.x+threadIdx.x; i < total; i += (size_t)gridDim.x*blockDim.x){
    int n = (int)(i / K), k = (int)(i - (size_t)n*K);
    float v = so2val(src, k*N + n, K0, h);
    unsigned short a,b; bfsplit(v,a,b); dh[i]=a; dl[i]=b;
  }
}
// dst: Bt[n][k] from plain row-major W[K][N]
__global__ void k_wsplit_plain(const float* __restrict__ src, unsigned short* __restrict__ dh,
                               unsigned short* __restrict__ dl, int N, int K){
  size_t total = (size_t)N*K;
  for (size_t i = (size_t)blockIdx.x*blockDim.x+threadIdx.x; i < total; i += (size_t)gridDim.x*blockDim.x){
    int n = (int)(i / K), k = (int)(i - (size_t)n*K);
    float v = src[(size_t)k*N + n];
    unsigned short a,b; bfsplit(v,a,b); dh[i]=a; dl[i]=b;
  }
}

// ---------------- CSR over tgt ----------------
__global__ void k_csr_count(const int* __restrict__ ei, int* __restrict__ cnt){
  int e = blockIdx.x*256+threadIdx.x;
  if (e < E_) atomicAdd(&cnt[ei[E_+e]], 1);
}
__global__ __launch_bounds__(1024) void k_csr_scan(const int* __restrict__ cnt,
                                                   int* __restrict__ off, int* __restrict__ pos){
  __shared__ int tmp[NNODE];
  int t = threadIdx.x; int v = cnt[t]; tmp[t] = v; __syncthreads();
  for (int d=1; d<NNODE; d<<=1){
    int add = (t>=d) ? tmp[t-d] : 0; __syncthreads();
    tmp[t] += add; __syncthreads();
  }
  int incl = tmp[t]; int excl = incl - v;
  off[t] = excl; pos[t] = excl;
  if (t == NNODE-1) off[NNODE] = incl;
}
__global__ void k_csr_fill(const int* __restrict__ ei, int* __restrict__ pos, int* __restrict__ edges){
  int e = blockIdx.x*256+threadIdx.x;
  if (e < E_){ int t = ei[E_+e]; int p = atomicAdd(&pos[t],1); edges[p] = e; }
}

// ---------------- radial MLP layers 1+2 (fused, 8 edges/block), bf16-split output ----
__global__ __launch_bounds__(128) void k_radial(const float* __restrict__ ed, const int* __restrict__ an,
   const int* __restrict__ ei, const float* __restrict__ semb, const float* __restrict__ temb,
   const float* __restrict__ w1, const float* __restrict__ b1, const float* __restrict__ g1, const float* __restrict__ bt1,
   const float* __restrict__ w2, const float* __restrict__ b2, const float* __restrict__ g2, const float* __restrict__ bt2,
   unsigned short* __restrict__ h2H, unsigned short* __restrict__ h2L)
{
  __shared__ float xs[EPB][EIN_];
  __shared__ float h1s[EPB][ECHN];
  __shared__ int se[EPB], te[EPB];
  __shared__ float rb[EPB][2][2];
  int tid = threadIdx.x; int eb = blockIdx.x*EPB;
  if (tid < EPB){ int e = eb+tid; se[tid] = an[ei[e]]; te[tid] = an[ei[E_+e]]; }
  __syncthreads();
  for (int i = tid; i < EPB*EIN_; i += 128){
    int el = i/EIN_, k = i - el*EIN_; int e = eb+el; float v;
    if (k < DDIST_) v = ed[(size_t)e*DDIST_ + k];
    else if (k < DDIST_+ECHN) v = semb[se[el]*ECHN + (k-DDIST_)];
    else v = temb[te[el]*ECHN + (k-DDIST_-ECHN)];
    xs[el][k] = v;
  }
  __syncthreads();
  int o = tid, lane = tid&63, wv = tid>>6;
  float gv = g1[o], bv = bt1[o], bb = b1[o];
  float acc[EPB];
  #pragma unroll
  for (int e=0;e<EPB;e++) acc[e] = bb;
  for (int k=0;k<EIN_;k++){
    float w = w1[k*ECHN + o];
    #pragma unroll
    for (int e=0;e<EPB;e++) acc[e] = fmaf(xs[e][k], w, acc[e]);
  }
  #pragma unroll
  for (int e=0;e<EPB;e++){
    float s1 = waveSum64(acc[e]);
    float s2 = waveSum64(acc[e]*acc[e]);
    if (lane==0){ rb[e][wv][0]=s1; rb[e][wv][1]=s2; }
  }
  __syncthreads();
  #pragma unroll
  for (int e=0;e<EPB;e++){
    float s1 = rb[e][0][0]+rb[e][1][0];
    float s2 = rb[e][0][1]+rb[e][1][1];
    float mu = s1*(1.f/128.f), var = s2*(1.f/128.f)-mu*mu;
    float a = (acc[e]-mu)*rsqrtf(var+1e-5f)*gv + bv;
    h1s[e][o] = silu_(a);
  }
  __syncthreads();
  float gv2 = g2[o], bv2 = bt2[o], bb2 = b2[o];
  #pragma unroll
  for (int e=0;e<EPB;e++) acc[e] = bb2;
  for (int k=0;k<ECHN;k++){
    float w = w2[k*ECHN + o];
    #pragma unroll
    for (int e=0;e<EPB;e++) acc[e] = fmaf(h1s[e][k], w, acc[e]);
  }
  #pragma unroll
  for (int e=0;e<EPB;e++){
    float s1 = waveSum64(acc[e]);
    float s2 = waveSum64(acc[e]*acc[e]);
    if (lane==0){ rb[e][wv][0]=s1; rb[e][wv][1]=s2; }
  }
  __syncthreads();
  #pragma unroll
  for (int e=0;e<EPB;e++){
    float s1 = rb[e][0][0]+rb[e][1][0];
    float s2 = rb[e][0][1]+rb[e][1][1];
    float mu = s1*(1.f/128.f), var = s2*(1.f/128.f)-mu*mu;
    float a = (acc[e]-mu)*rsqrtf(var+1e-5f)*gv2 + bv2;
    float hv = silu_(a);
    unsigned short hh, ll; bfsplit(hv, hh, ll);
    h2H[(size_t)(eb+e)*ECHN + o] = hh;
    h2L[(size_t)(eb+e)*ECHN + o] = ll;
  }
}

// ---------------- wigner rotate (+PERM_M) * rad, per-edge -> bf16 hi/lo planes ------
__global__ __launch_bounds__(256) void k_wigmm(const float* __restrict__ x, const int* __restrict__ ei,
    const float* __restrict__ wig, const float* __restrict__ rad,
    unsigned short* __restrict__ AmmH, unsigned short* __restrict__ AmmL, int e0)
{
  int e = e0 + blockIdx.x;
  int c = threadIdx.x;
  int nid = (c < CC) ? ei[e] : ei[E_ + e];
  int cc = c & (CC-1);
  const float* xb = x + (size_t)nid*NCOEF*CC + cc;
  float xr[NCOEF];
  #pragma unroll
  for (int n=0;n<NCOEF;n++) xr[n] = xb[n*CC];
  const float* wb = wig + (size_t)e*MRED*NCOEF;
  const float* rbp = rad + (size_t)blockIdx.x*RADTOT;
  unsigned short* ah = AmmH + (size_t)blockIdx.x*AMMW;
  unsigned short* al = AmmL + (size_t)blockIdx.x*AMMW;
  #pragma unroll
  for (int mi=0; mi<MRED; mi++){
    const float* wr = wb + PERM_M_c[mi]*NCOEF;
    float acc = 0.f;
    #pragma unroll
    for (int n=0;n<NCOEF;n++) acc = fmaf(wr[n], xr[n], acc);
    float v = acc * rbp[RADOFF_c[mi] + c];
    unsigned short hh, ll; bfsplit(v, hh, ll);
    ah[mi*C2 + c] = hh; al[mi*C2 + c] = ll;
  }
}

// ---------------- epilogue functors ----------------
struct EpiRad { float* out; __device__ void operator()(int m,int n,float v) const {
  out[(size_t)m*RADTOT + n] = v; } };
struct EpiG1 { float* xextra; float* msgbuf; int e0; __device__ void operator()(int m,int n,float v) const {
  int e = e0+m;
  if (n < EXTRA_) xextra[(size_t)e*EXTRA_ + n] = v;
  else msgbuf[(size_t)e*MSGW + (n-EXTRA_)] = v; } };
struct EpiMsg { float* msgbuf; int e0; int off; __device__ void operator()(int m,int n,float v) const {
  msgbuf[(size_t)(e0+m)*MSGW + off + n] = v; } };
struct EpiVal { float* val; const float* alpha; int e0; int off; __device__ void operator()(int m,int n,float v) const {
  int head = ((off+n)&127)>>4;
  float a = alpha[(size_t)(e0+m)*NHEAD + head];
  val[(size_t)m*VALW + off + n] = v*a; } };

// ---------------- bf16-plane MFMA GEMM: C = (Ah+Al) * (Bh+Bl), 3-product ----------
// A pre-split planes [M][sA]; B pre-split planes Bt[n][k]. 128x128 tile, 4 waves 2x2,
// 16x16x32 bf16 MFMA. LDS stages A (copy only, no VALU split); regs prefetch next slab.
template<class Epi>
__global__ __launch_bounds__(256) void gemmMF(const unsigned short* __restrict__ Ah,
    const unsigned short* __restrict__ Al, int sA,
    const unsigned short* __restrict__ Bh, const unsigned short* __restrict__ Bl,
    int N, int K, const float* __restrict__ bias, Epi epi)
{
  __shared__ unsigned short Ah_s[128][40];
  __shared__ unsigned short Al_s[128][40];
  int tid = threadIdx.x;
  int bm = blockIdx.y*128, bn = blockIdx.x*128;
  int wl = tid & 63, wid = tid >> 6;
  int wm = wid >> 1, wn = wid & 1;
  int lrow = wl & 15, lk = (wl >> 4) * 8;
  int srow = tid >> 1, scolb = (tid & 1) * 16;
  const unsigned short* ApH = Ah + (size_t)(bm + srow)*sA + scolb;
  const unsigned short* ApL = Al + (size_t)(bm + srow)*sA + scolb;

  f32x4 acc[4][4];
  #pragma unroll
  for (int i=0;i<4;i++)
    #pragma unroll
    for (int j=0;j<4;j++){ f32x4 z = {0.f,0.f,0.f,0.f}; acc[i][j] = z; }

  s16x8 sh0 = *(const s16x8*)(ApH);
  s16x8 sh1 = *(const s16x8*)(ApH + 8);
  s16x8 sl0 = *(const s16x8*)(ApL);
  s16x8 sl1 = *(const s16x8*)(ApL + 8);

  for (int k0 = 0; k0 < K; k0 += 32){
    *(s16x8*)&Ah_s[srow][scolb]   = sh0;
    *(s16x8*)&Ah_s[srow][scolb+8] = sh1;
    *(s16x8*)&Al_s[srow][scolb]   = sl0;
    *(s16x8*)&Al_s[srow][scolb+8] = sl1;
    __syncthreads();
    if (k0 + 32 < K){
      sh0 = *(const s16x8*)(ApH + k0+32);
      sh1 = *(const s16x8*)(ApH + k0+40);
      sl0 = *(const s16x8*)(ApL + k0+32);
      sl1 = *(const s16x8*)(ApL + k0+40);
    }
    s16x8 bh[4], bl[4];
    #pragma unroll
    for (int ni=0;ni<4;ni++){
      size_t boff = (size_t)(bn + wn*64 + ni*16 + lrow)*K + k0 + lk;
      bh[ni] = *(const s16x8*)(Bh + boff);
      bl[ni] = *(const s16x8*)(Bl + boff);
    }
    s16x8 ah[4], al[4];
    #pragma unroll
    for (int mi=0;mi<4;mi++){
      ah[mi] = *(s16x8*)&Ah_s[wm*64 + mi*16 + lrow][lk];
      al[mi] = *(s16x8*)&Al_s[wm*64 + mi*16 + lrow][lk];
    }
    #pragma unroll
    for (int ni=0;ni<4;ni++){
      #pragma unroll
      for (int mi=0;mi<4;mi++){
        acc[mi][ni] = __builtin_amdgcn_mfma_f32_16x16x32_bf16(ah[mi], bh[ni], acc[mi][ni], 0,0,0);
        acc[mi][ni] = __builtin_amdgcn_mfma_f32_16x16x32_bf16(ah[mi], bl[ni], acc[mi][ni], 0,0,0);
        acc[mi][ni] = __builtin_amdgcn_mfma_f32_16x16x32_bf16(al[mi], bh[ni], acc[mi][ni], 0,0,0);
      }
    }
    __syncthreads();
  }
  // epilogue: C/D mapping col=lane&15, row=(lane>>4)*4+reg  [m89-verified]
  #pragma unroll
  for (int mi=0;mi<4;mi++)
    #pragma unroll
    for (int ni=0;ni<4;ni++){
      #pragma unroll
      for (int j=0;j<4;j++){
        int m = bm + wm*64 + mi*16 + (wl>>4)*4 + j;
        int n = bn + wn*64 + ni*16 + (wl&15);
        float v = acc[mi][ni][j] + (bias ? bias[n] : 0.f);
        epi(m, n, v);
      }
    }
}

// ---------------- attention: LN + gate + logit ----------------
__global__ __launch_bounds__(64) void k_alpha(const float* __restrict__ xextra,
    const float* __restrict__ ag, const float* __restrict__ ab,
    const float* __restrict__ adot, float* __restrict__ logit)
{
  int e = blockIdx.x; int t = threadIdx.x;
  float gv = ag[t], bv = ab[t];
  #pragma unroll
  for (int h=0; h<NHEAD; h++){
    float xv = xextra[(size_t)e*EXTRA_ + h*ACH + t];
    float s1 = waveSum64(xv), s2 = waveSum64(xv*xv);
    float mu = s1*(1.f/64.f), var = s2*(1.f/64.f)-mu*mu;
    float a = (xv-mu)*rsqrtf(var+1e-5f)*gv + bv;
    float sg = 1.f/(1.f+__expf(-a));
    float a2 = 0.6f*a + 0.4f*a*(2.f*sg-1.f);
    float p = a2 * adot[h*ACH + t];
    float ps = waveSum64(p);
    if (t==0) logit[(size_t)e*NHEAD + h] = ps;
  }
}
__global__ __launch_bounds__(64) void k_softmax(const int* __restrict__ coff, const int* __restrict__ cedges,
    const float* __restrict__ logit, float* __restrict__ alpha)
{
  int node = blockIdx.x; int t = threadIdx.x;
  int s = coff[node], en = coff[node+1];
  if (t < NHEAD){
    float m = -1e30f;
    for (int i=s;i<en;i++){ int e = cedges[i]; m = fmaxf(m, logit[(size_t)e*NHEAD+t]); }
    float den = 0.f;
    for (int i=s;i<en;i++){ int e = cedges[i]; den += __expf(logit[(size_t)e*NHEAD+t]-m); }
    den += 1e-16f;
    for (int i=s;i<en;i++){ int e = cedges[i];
      alpha[(size_t)e*NHEAD+t] = __expf(logit[(size_t)e*NHEAD+t]-m)/den; }
  }
}

// ---------------- grid act: 4 edges/block, writes bf16 hi/lo msg planes -------------
__global__ __launch_bounds__(256) void k_grid(const float* __restrict__ msgbuf,
      const float* __restrict__ xextra,
      const float* __restrict__ tgp, const float* __restrict__ fgp,
      unsigned short* __restrict__ msgH, unsigned short* __restrict__ msgL)
{
  int e = blockIdx.x*4 + (threadIdx.x>>6); int c = threadIdx.x & 63;
  const float* mb = msgbuf + (size_t)e*MSGW;
  float msg[MRED], tens[MRED];
  #pragma unroll
  for (int k=0;k<MRED;k++){ msg[k] = mb[k*HH + c]; tens[k] = 0.f; }
  for (int ba=0; ba<RESBA; ba++){
    const float* tg = tgp + ba*MRED;
    const float* fg = fgp + ba*MRED;
    float g = 0.f;
    #pragma unroll
    for (int k=0;k<MRED;k++) g = fmaf(tg[k], msg[k], g);
    g = silu_(g);
    #pragma unroll
    for (int k=1;k<MRED;k++) tens[k] = fmaf(fg[k], g, tens[k]);
  }
  unsigned short hh, ll;
  float r0 = silu_(xextra[(size_t)e*EXTRA_ + ALPHACH_ + c]);
  bfsplit(r0, hh, ll);
  msgH[(size_t)e*MSGW + c] = hh; msgL[(size_t)e*MSGW + c] = ll;
  #pragma unroll
  for (int k=1;k<MRED;k++){
    bfsplit(tens[k], hh, ll);
    msgH[(size_t)e*MSGW + k*HH + c] = hh;
    msgL[(size_t)e*MSGW + k*HH + c] = ll;
  }
}

// ---------------- wigner^T scatter into node (per chunk, CSR-owned rows) -----------
__global__ __launch_bounds__(128) void k_scatter(const int* __restrict__ coff, const int* __restrict__ cedges,
      const float* __restrict__ wig, const float* __restrict__ valc, float* __restrict__ node,
      int e0, int e1)
{
  int nd = blockIdx.x; int c = threadIdx.x;
  int s = coff[nd], en = coff[nd+1];
  float acc[NCOEF];
  #pragma unroll
  for (int q=0;q<NCOEF;q++) acc[q]=0.f;
  bool any=false;
  for (int i=s;i<en;i++){
    int e = cedges[i];
    if (e < e0 || e >= e1) continue;
    any = true;
    const float* vb = valc + (size_t)(e-e0)*VALW + c;
    float v[MRED];
    #pragma unroll
    for (int r=0;r<MRED;r++) v[r] = vb[r*128];
    const float* wb = wig + (size_t)e*MRED*NCOEF;
    #pragma unroll
    for (int r=0;r<MRED;r++){
      const float* wr = wb + PERM_M_c[r]*NCOEF;
      #pragma unroll
      for (int q=0;q<NCOEF;q++) acc[q] = fmaf(wr[q], v[r], acc[q]);
    }
  }
  if (any){
    float* nb = node + (size_t)nd*NCOEF*128 + c;
    #pragma unroll
    for (int q=0;q<NCOEF;q++) nb[q*128] += acc[q];
  }
}

// ---------------- final projection (pwt pre-transposed [l][v][o]) ----------------
__global__ __launch_bounds__(128) void k_proj(const float* __restrict__ node, const float* __restrict__ pwt,
      const float* __restrict__ pb, float* __restrict__ out)
{
  int b = blockIdx.x, l = blockIdx.y;
  int o = threadIdx.x;
  int i0 = l*l; int nrow = 2*l+1;
  __shared__ float ns[13][128];
  for (int r=0;r<nrow;r++) ns[r][o] = node[((size_t)b*NCOEF + i0 + r)*128 + o];
  __syncthreads();
  float acc[13];
  #pragma unroll
  for (int r=0;r<13;r++) acc[r] = (i0+r==0) ? pb[o] : 0.f;
  const float* pw = pwt + (size_t)l*16384 + o;
  for (int v=0;v<128;v++){
    float w = pw[v*128];
    #pragma unroll
    for (int r=0;r<13;r++) if (r<nrow) acc[r] = fmaf(ns[r][v], w, acc[r]);
  }
  #pragma unroll
  for (int r=0;r<13;r++) if (r<nrow) out[((size_t)b*NCOEF + i0 + r)*128 + o] = acc[r];
}

// =======================================================================================
static inline size_t al256(size_t x){ return (x+255)&~(size_t)255; }

extern "C" void kernel_launch(void* const* d_in, const int* in_sizes, int n_in,
                              void* d_out, int out_size, void* d_ws, size_t ws_size,
                              hipStream_t stream) {
  const float* x     = (const float*)d_in[0];
  const int*   an    = (const int*)  d_in[1];
  const float* ed    = (const float*)d_in[2];
  const int*   ei    = (const int*)  d_in[3];
  const float* semb  = (const float*)d_in[4];
  const float* temb  = (const float*)d_in[5];
  const float* w1    = (const float*)d_in[6];
  const float* b1    = (const float*)d_in[7];
  const float* g1    = (const float*)d_in[8];
  const float* bt1   = (const float*)d_in[9];
  const float* w2    = (const float*)d_in[10];
  const float* b2    = (const float*)d_in[11];
  const float* g2    = (const float*)d_in[12];
  const float* bt2   = (const float*)d_in[13];
  const float* w3    = (const float*)d_in[14];
  const float* b3    = (const float*)d_in[15];
  const float* wig   = (const float*)d_in[16];
  const float* c1m0w = (const float*)d_in[17];
  const float* c1m0b = (const float*)d_in[18];
  const float* c1m1w = (const float*)d_in[19];
  const float* c1m2w = (const float*)d_in[20];
  const float* ag    = (const float*)d_in[21];
  const float* abv   = (const float*)d_in[22];
  const float* adot  = (const float*)d_in[23];
  const float* tg    = (const float*)d_in[24];
  const float* fg    = (const float*)d_in[25];
  const float* c2m0w = (const float*)d_in[26];
  const float* c2m0b = (const float*)d_in[27];
  const float* c2m1w = (const float*)d_in[28];
  const float* c2m2w = (const float*)d_in[29];
  const float* pw    = (const float*)d_in[30];
  const float* pb    = (const float*)d_in[31];
  float* out = (float*)d_out;

  char* base = (char*)d_ws;
  size_t off = 0;
  auto allocf = [&](size_t n)->float* { float* p = (float*)(base+off); off += al256(n*sizeof(float)); return p; };
  auto allocu = [&](size_t n)->unsigned short* { unsigned short* p = (unsigned short*)(base+off); off += al256(n*2); return p; };
  // bf16 hi/lo weight planes, layout Bt[n][k]
  const size_t n1e = (size_t)768*3072, n2e = (size_t)640*2560, n3e = (size_t)1536*768,
               n4e = (size_t)1280*640, g1e = (size_t)1024*1792, v0e = (size_t)896*448,
               rre = (size_t)4608*128;
  unsigned short* Wt1h = allocu(n1e); unsigned short* Wt1l = allocu(n1e);
  unsigned short* Wt2h = allocu(n2e); unsigned short* Wt2l = allocu(n2e);
  unsigned short* Wt3h = allocu(n3e); unsigned short* Wt3l = allocu(n3e);
  unsigned short* Wt4h = allocu(n4e); unsigned short* Wt4l = allocu(n4e);
  unsigned short* Wg1h = allocu(g1e); unsigned short* Wg1l = allocu(g1e);
  unsigned short* Wv0h = allocu(v0e); unsigned short* Wv0l = allocu(v0e);
  unsigned short* Wrh  = allocu(rre); unsigned short* Wrl  = allocu(rre);
  // bf16 hi/lo activation planes
  unsigned short* h2H  = allocu((size_t)E_*ECHN);
  unsigned short* h2L  = allocu((size_t)E_*ECHN);
  unsigned short* msgH = allocu((size_t)E_*MSGW);
  unsigned short* msgL = allocu((size_t)E_*MSGW);
  float* tgp    = allocf(RESBA*MRED);
  float* fgp    = allocf(RESBA*MRED);
  float* pwt    = allocf((size_t)7*128*128);
  float* xextra = allocf((size_t)E_*EXTRA_);
  float* logit  = allocf((size_t)E_*NHEAD);
  float* alphab = allocf((size_t)E_*NHEAD);
  float* msgbuf = allocf((size_t)E_*MSGW);
  int* csr_cnt   = (int*)allocf(NNODE);
  int* csr_off   = (int*)allocf(NNODE+1);
  int* csr_pos   = (int*)allocf(NNODE);
  int* csr_edges = (int*)allocf(E_);
  float* nodeb  = allocf((size_t)NNODE*NCOEF*128);
  size_t fixed_end = off;

  // chunk size: phase-1 temps (rad fp32 + Amm bf16 hi/lo) union with phase-3 val fp32
  int CH = 2048;
  for (;;){
    size_t radb = al256((size_t)CH*RADTOT*4);
    size_t ammb = 2*al256((size_t)CH*AMMW*2);
    size_t valb = al256((size_t)CH*VALW*4);
    size_t big = radb+ammb; if (valb > big) big = valb;
    if (fixed_end + big <= ws_size || CH == 256) break;
    CH >>= 1;
  }
  float* rad_c = (float*)(base + fixed_end);
  unsigned short* AmmH = (unsigned short*)(base + fixed_end + al256((size_t)CH*RADTOT*4));
  unsigned short* AmmL = (unsigned short*)(base + fixed_end + al256((size_t)CH*RADTOT*4) + al256((size_t)CH*AMMW*2));
  float* val_c = (float*)(base + fixed_end);   // aliases rad_c (disjoint phases)

  // ---- prep: grid tables, weight split/transpose, CSR, radial ----
  k_gridtab<<<512, 256, 0, stream>>>(tg, fg, pw, tgp, fgp, pwt);
  k_wsplit_so2<<<2048, 256, 0, stream>>>(c1m1w, Wt1h, Wt1l, 768, 3072, 1536, 384);
  k_wsplit_so2<<<2048, 256, 0, stream>>>(c1m2w, Wt2h, Wt2l, 640, 2560, 1280, 320);
  k_wsplit_so2<<<1024, 256, 0, stream>>>(c2m1w, Wt3h, Wt3l, 1536, 768, 384, 768);
  k_wsplit_so2<<<1024, 256, 0, stream>>>(c2m2w, Wt4h, Wt4l, 1280, 640, 320, 640);
  k_wsplit_plain<<<2048, 256, 0, stream>>>(c1m0w, Wg1h, Wg1l, 1024, 1792);
  k_wsplit_plain<<<512, 256, 0, stream>>>(c2m0w, Wv0h, Wv0l, 896, 448);
  k_wsplit_plain<<<512, 256, 0, stream>>>(w3, Wrh, Wrl, RADTOT, ECHN);
  hipMemsetAsync(csr_cnt, 0, NNODE*sizeof(int), stream);
  k_csr_count<<<E_/256, 256, 0, stream>>>(ei, csr_cnt);
  k_csr_scan<<<1, NNODE, 0, stream>>>(csr_cnt, csr_off, csr_pos);
  k_csr_fill<<<E_/256, 256, 0, stream>>>(ei, csr_pos, csr_edges);
  k_radial<<<E_/EPB, 128, 0, stream>>>(ed, an, ei, semb, temb,
                                       w1, b1, g1, bt1, w2, b2, g2, bt2, h2H, h2L);

  // ---- phase 1: per chunk: rad, wigner-rotate(split), SO2 conv #1 (bf16 MFMA) ----
  for (int e0 = 0; e0 < E_; e0 += CH){
    gemmMF<EpiRad><<<dim3(RADTOT/128, CH/128), 256, 0, stream>>>(
        h2H + (size_t)e0*ECHN, h2L + (size_t)e0*ECHN, ECHN, Wrh, Wrl, RADTOT, ECHN, b3, EpiRad{rad_c});
    k_wigmm<<<CH, 256, 0, stream>>>(x, ei, wig, rad_c, AmmH, AmmL, e0);
    gemmMF<EpiG1><<<dim3(1024/128, CH/128), 256, 0, stream>>>(
        AmmH, AmmL, AMMW, Wg1h, Wg1l, 1024, 1792, c1m0b, EpiG1{xextra, msgbuf, e0});
    gemmMF<EpiMsg><<<dim3(768/128, CH/128), 256, 0, stream>>>(
        AmmH + 1792, AmmL + 1792, AMMW, Wt1h, Wt1l, 768, 3072, nullptr, EpiMsg{msgbuf, e0, 448});
    gemmMF<EpiMsg><<<dim3(640/128, CH/128), 256, 0, stream>>>(
        AmmH + 4864, AmmL + 4864, AMMW, Wt2h, Wt2l, 640, 2560, nullptr, EpiMsg{msgbuf, e0, 1216});
  }

  // ---- phase 2: attention softmax + grid activation (writes split msg planes) ----
  k_alpha<<<E_, 64, 0, stream>>>(xextra, ag, abv, adot, logit);
  k_softmax<<<NNODE, 64, 0, stream>>>(csr_off, csr_edges, logit, alphab);
  k_grid<<<E_/4, 256, 0, stream>>>(msgbuf, xextra, tgp, fgp, msgH, msgL);

  // ---- phase 3+4: per chunk: SO2 conv #2 (alpha-scaled, MFMA) + wigner^T scatter ----
  hipMemsetAsync(nodeb, 0, (size_t)NNODE*NCOEF*128*sizeof(float), stream);
  for (int e0 = 0; e0 < E_; e0 += CH){
    gemmMF<EpiVal><<<dim3(896/128, CH/128), 256, 0, stream>>>(
        msgH + (size_t)e0*MSGW, msgL + (size_t)e0*MSGW, MSGW, Wv0h, Wv0l, 896, 448, c2m0b,
        EpiVal{val_c, alphab, e0, 0});
    gemmMF<EpiVal><<<dim3(1536/128, CH/128), 256, 0, stream>>>(
        msgH + (size_t)e0*MSGW + 448, msgL + (size_t)e0*MSGW + 448, MSGW, Wt3h, Wt3l, 1536, 768, nullptr,
        EpiVal{val_c, alphab, e0, 896});
    gemmMF<EpiVal><<<dim3(1280/128, CH/128), 256, 0, stream>>>(
        msgH + (size_t)e0*MSGW + 1216, msgL + (size_t)e0*MSGW + 1216, MSGW, Wt4h, Wt4l, 1280, 640, nullptr,
        EpiVal{val_c, alphab, e0, 2432});
    k_scatter<<<NNODE, 128, 0, stream>>>(csr_off, csr_edges, wig, val_c, nodeb, e0, e0+CH);
  }

  // ---- phase 5: projection ----
  k_proj<<<dim3(NNODE, 7), 128, 0, stream>>>(nodeb, pwt, pb, out);
}

// Round 13
// 3551.159 us; speedup vs baseline: 2.1243x; 2.1243x over previous
//
#include <hip/hip_runtime.h>
#include <math.h>

#define E_ 8192
#define NNODE 1024
#define NCOEF 49
#define MRED 29
#define CC 128
#define C2 256
#define HH 64
#define NHEAD 8
#define ACH 64
#define RESBA 196
#define DDIST_ 512
#define ECHN 128
#define EIN_ 768
#define EXTRA_ 576
#define ALPHACH_ 512
#define RADTOT 4608
#define AMMW 7424   /* 29*256 */
#define MSGW 1856   /* 29*64 */
#define VALW 3712   /* 29*128 */
#define EPB 8

typedef __attribute__((ext_vector_type(8))) short s16x8;
typedef __attribute__((ext_vector_type(4))) float f32x4;

__constant__ int PERM_M_c[MRED] = {0,2,6,11,16,21,26, 3,7,12,17,22,27, 1,5,10,15,20,25, 8,13,18,23,28, 4,9,14,19,24};
__constant__ int RADOFF_c[MRED] = {0,256,512,768,1024,1280,1536,
                                   1792,2048,2304,2560,2816,3072,
                                   1792,2048,2304,2560,2816,3072,
                                   3328,3584,3840,4096,4352,
                                   3328,3584,3840,4096,4352};

__device__ inline float waveSum64(float v){
  #pragma unroll
  for (int d=32; d>0; d>>=1) v += __shfl_xor(v, d, 64);
  return v;
}
__device__ inline float silu_(float x){ return x/(1.f+__expf(-x)); }

// split fp32 -> bf16 hi + bf16 lo (RNE both); a ~= hi + lo, |err| ~ 2^-17 rel
__device__ inline void bfsplit(float x, unsigned short& h, unsigned short& l){
  unsigned u = __float_as_uint(x);
  unsigned hb = (u + 0x7FFFu + ((u>>16)&1u)) >> 16;
  float hf = __uint_as_float(hb << 16);
  float lo = x - hf;
  unsigned ul = __float_as_uint(lo);
  h = (unsigned short)hb;
  l = (unsigned short)((ul + 0x7FFFu + ((ul>>16)&1u)) >> 16);
}
__device__ inline float bfjoin(unsigned short h, unsigned short l){
  return __uint_as_float((unsigned)h<<16) + __uint_as_float((unsigned)l<<16);
}

// ---------------- prep: grid tables + proj transpose ----------------
__global__ void k_gridtab(const float* __restrict__ tg, const float* __restrict__ fg,
                          const float* __restrict__ pw,
                          float* __restrict__ tgp, float* __restrict__ fgp, float* __restrict__ pwt)
{
  const int ng = RESBA*MRED, np = 7*128*128;
  int total = 2*ng+np;
  for (int i = blockIdx.x*blockDim.x+threadIdx.x; i < total; i += gridDim.x*blockDim.x){
    int j = i;
    if (j < ng){ int ba=j/MRED,k=j-ba*MRED; tgp[j] = tg[ba*MRED + PERM_M_c[k]]; continue; } j -= ng;
    if (j < ng){ int ba=j/MRED,k=j-ba*MRED; fgp[j] = fg[ba*MRED + PERM_M_c[k]]; continue; } j -= ng;
    { int l = j/16384, r = j-l*16384, v = r>>7, o = r&127; pwt[j] = pw[l*16384 + o*128 + v]; }
  }
}

// SO2 folded weight value: Wbig = [[Wr, Wi], [-Wi, Wr]], idx = k*N + n (row-major KxN)
__device__ inline float so2val(const float* __restrict__ w, int idx, int K0, int h){
  int two_h = 2*h; int k = idx/two_h, jj = idx - k*two_h;
  if (jj < h) return (k<K0) ? w[k*two_h + jj] : -w[(k-K0)*two_h + (h+jj)];
  else        return (k<K0) ? w[k*two_h + jj] :  w[(k-K0)*two_h + (jj-h)];
}
// dst: Bt[n][k] bf16 planes from folded SO2 weight (KxN logical)
__global__ void k_wsplit_so2(const float* __restrict__ src, unsigned short* __restrict__ dh,
                             unsigned short* __restrict__ dl, int N, int K, int K0, int h){
  size_t total = (size_t)N*K;
  for (size_t i = (size_t)blockIdx.x*blockDim.x+threadIdx.x; i < total; i += (size_t)gridDim.x*blockDim.x){
    int n = (int)(i / K), k = (int)(i - (size_t)n*K);
    float v = so2val(src, k*N + n, K0, h);
    unsigned short a,b; bfsplit(v,a,b); dh[i]=a; dl[i]=b;
  }
}
// dst: Bt[n][k] from plain row-major W[K][N]
__global__ void k_wsplit_plain(const float* __restrict__ src, unsigned short* __restrict__ dh,
                               unsigned short* __restrict__ dl, int N, int K){
  size_t total = (size_t)N*K;
  for (size_t i = (size_t)blockIdx.x*blockDim.x+threadIdx.x; i < total; i += (size_t)gridDim.x*blockDim.x){
    int n = (int)(i / K), k = (int)(i - (size_t)n*K);
    float v = src[(size_t)k*N + n];
    unsigned short a,b; bfsplit(v,a,b); dh[i]=a; dl[i]=b;
  }
}

// ---------------- CSR over tgt ----------------
__global__ void k_csr_count(const int* __restrict__ ei, int* __restrict__ cnt){
  int e = blockIdx.x*256+threadIdx.x;
  if (e < E_) atomicAdd(&cnt[ei[E_+e]], 1);
}
__global__ __launch_bounds__(1024) void k_csr_scan(const int* __restrict__ cnt,
                                                   int* __restrict__ off, int* __restrict__ pos){
  __shared__ int tmp[NNODE];
  int t = threadIdx.x; int v = cnt[t]; tmp[t] = v; __syncthreads();
  for (int d=1; d<NNODE; d<<=1){
    int add = (t>=d) ? tmp[t-d] : 0; __syncthreads();
    tmp[t] += add; __syncthreads();
  }
  int incl = tmp[t]; int excl = incl - v;
  off[t] = excl; pos[t] = excl;
  if (t == NNODE-1) off[NNODE] = incl;
}
__global__ void k_csr_fill(const int* __restrict__ ei, int* __restrict__ pos, int* __restrict__ edges){
  int e = blockIdx.x*256+threadIdx.x;
  if (e < E_){ int t = ei[E_+e]; int p = atomicAdd(&pos[t],1); edges[p] = e; }
}

// ---------------- radial MLP layers 1+2 (fused, 8 edges/block), bf16-split output ----
__global__ __launch_bounds__(128) void k_radial(const float* __restrict__ ed, const int* __restrict__ an,
   const int* __restrict__ ei, const float* __restrict__ semb, const float* __restrict__ temb,
   const float* __restrict__ w1, const float* __restrict__ b1, const float* __restrict__ g1, const float* __restrict__ bt1,
   const float* __restrict__ w2, const float* __restrict__ b2, const float* __restrict__ g2, const float* __restrict__ bt2,
   unsigned short* __restrict__ h2H, unsigned short* __restrict__ h2L)
{
  __shared__ float xs[EPB][EIN_];
  __shared__ float h1s[EPB][ECHN];
  __shared__ int se[EPB], te[EPB];
  __shared__ float rb[EPB][2][2];
  int tid = threadIdx.x; int eb = blockIdx.x*EPB;
  if (tid < EPB){ int e = eb+tid; se[tid] = an[ei[e]]; te[tid] = an[ei[E_+e]]; }
  __syncthreads();
  for (int i = tid; i < EPB*EIN_; i += 128){
    int el = i/EIN_, k = i - el*EIN_; int e = eb+el; float v;
    if (k < DDIST_) v = ed[(size_t)e*DDIST_ + k];
    else if (k < DDIST_+ECHN) v = semb[se[el]*ECHN + (k-DDIST_)];
    else v = temb[te[el]*ECHN + (k-DDIST_-ECHN)];
    xs[el][k] = v;
  }
  __syncthreads();
  int o = tid, lane = tid&63, wv = tid>>6;
  float gv = g1[o], bv = bt1[o], bb = b1[o];
  float acc[EPB];
  #pragma unroll
  for (int e=0;e<EPB;e++) acc[e] = bb;
  for (int k=0;k<EIN_;k++){
    float w = w1[k*ECHN + o];
    #pragma unroll
    for (int e=0;e<EPB;e++) acc[e] = fmaf(xs[e][k], w, acc[e]);
  }
  #pragma unroll
  for (int e=0;e<EPB;e++){
    float s1 = waveSum64(acc[e]);
    float s2 = waveSum64(acc[e]*acc[e]);
    if (lane==0){ rb[e][wv][0]=s1; rb[e][wv][1]=s2; }
  }
  __syncthreads();
  #pragma unroll
  for (int e=0;e<EPB;e++){
    float s1 = rb[e][0][0]+rb[e][1][0];
    float s2 = rb[e][0][1]+rb[e][1][1];
    float mu = s1*(1.f/128.f), var = s2*(1.f/128.f)-mu*mu;
    float a = (acc[e]-mu)*rsqrtf(var+1e-5f)*gv + bv;
    h1s[e][o] = silu_(a);
  }
  __syncthreads();
  float gv2 = g2[o], bv2 = bt2[o], bb2 = b2[o];
  #pragma unroll
  for (int e=0;e<EPB;e++) acc[e] = bb2;
  for (int k=0;k<ECHN;k++){
    float w = w2[k*ECHN + o];
    #pragma unroll
    for (int e=0;e<EPB;e++) acc[e] = fmaf(h1s[e][k], w, acc[e]);
  }
  #pragma unroll
  for (int e=0;e<EPB;e++){
    float s1 = waveSum64(acc[e]);
    float s2 = waveSum64(acc[e]*acc[e]);
    if (lane==0){ rb[e][wv][0]=s1; rb[e][wv][1]=s2; }
  }
  __syncthreads();
  #pragma unroll
  for (int e=0;e<EPB;e++){
    float s1 = rb[e][0][0]+rb[e][1][0];
    float s2 = rb[e][0][1]+rb[e][1][1];
    float mu = s1*(1.f/128.f), var = s2*(1.f/128.f)-mu*mu;
    float a = (acc[e]-mu)*rsqrtf(var+1e-5f)*gv2 + bv2;
    float hv = silu_(a);
    unsigned short hh, ll; bfsplit(hv, hh, ll);
    h2H[(size_t)(eb+e)*ECHN + o] = hh;
    h2L[(size_t)(eb+e)*ECHN + o] = ll;
  }
}

// ---------------- wigner rotate (+PERM_M) * rad, per-edge -> bf16 hi/lo planes ------
__global__ __launch_bounds__(256) void k_wigmm(const float* __restrict__ x, const int* __restrict__ ei,
    const float* __restrict__ wig, const float* __restrict__ rad,
    unsigned short* __restrict__ AmmH, unsigned short* __restrict__ AmmL, int e0)
{
  int e = e0 + blockIdx.x;
  int c = threadIdx.x;
  int nid = (c < CC) ? ei[e] : ei[E_ + e];
  int cc = c & (CC-1);
  const float* xb = x + (size_t)nid*NCOEF*CC + cc;
  float xr[NCOEF];
  #pragma unroll
  for (int n=0;n<NCOEF;n++) xr[n] = xb[n*CC];
  const float* wb = wig + (size_t)e*MRED*NCOEF;
  const float* rbp = rad + (size_t)blockIdx.x*RADTOT;
  unsigned short* ah = AmmH + (size_t)blockIdx.x*AMMW;
  unsigned short* al = AmmL + (size_t)blockIdx.x*AMMW;
  #pragma unroll
  for (int mi=0; mi<MRED; mi++){
    const float* wr = wb + PERM_M_c[mi]*NCOEF;
    float acc = 0.f;
    #pragma unroll
    for (int n=0;n<NCOEF;n++) acc = fmaf(wr[n], xr[n], acc);
    float v = acc * rbp[RADOFF_c[mi] + c];
    unsigned short hh, ll; bfsplit(v, hh, ll);
    ah[mi*C2 + c] = hh; al[mi*C2 + c] = ll;
  }
}

// ---------------- rad GEMM epilogue ----------------
struct EpiRad { float* out; __device__ void operator()(int m,int n,float v) const {
  out[(size_t)m*RADTOT + n] = v; } };

// ---------------- bf16-plane MFMA GEMM core (single B, functor epi) ---------------
template<class Epi>
__global__ __launch_bounds__(256) void gemmMF(const unsigned short* __restrict__ Ah,
    const unsigned short* __restrict__ Al, int sA,
    const unsigned short* __restrict__ Bh, const unsigned short* __restrict__ Bl,
    int N, int K, const float* __restrict__ bias, Epi epi)
{
  __shared__ unsigned short Ah_s[128][40];
  __shared__ unsigned short Al_s[128][40];
  int tid = threadIdx.x;
  int bm = blockIdx.y*128, bn = blockIdx.x*128;
  int wl = tid & 63, wid = tid >> 6;
  int wm = wid >> 1, wn = wid & 1;
  int lrow = wl & 15, lk = (wl >> 4) * 8;
  int srow = tid >> 1, scolb = (tid & 1) * 16;
  const unsigned short* ApH = Ah + (size_t)(bm + srow)*sA + scolb;
  const unsigned short* ApL = Al + (size_t)(bm + srow)*sA + scolb;

  f32x4 acc[4][4];
  #pragma unroll
  for (int i=0;i<4;i++)
    #pragma unroll
    for (int j=0;j<4;j++){ f32x4 z = {0.f,0.f,0.f,0.f}; acc[i][j] = z; }

  s16x8 sh0 = *(const s16x8*)(ApH);
  s16x8 sh1 = *(const s16x8*)(ApH + 8);
  s16x8 sl0 = *(const s16x8*)(ApL);
  s16x8 sl1 = *(const s16x8*)(ApL + 8);

  for (int k0 = 0; k0 < K; k0 += 32){
    *(s16x8*)&Ah_s[srow][scolb]   = sh0;
    *(s16x8*)&Ah_s[srow][scolb+8] = sh1;
    *(s16x8*)&Al_s[srow][scolb]   = sl0;
    *(s16x8*)&Al_s[srow][scolb+8] = sl1;
    __syncthreads();
    if (k0 + 32 < K){
      sh0 = *(const s16x8*)(ApH + k0+32);
      sh1 = *(const s16x8*)(ApH + k0+40);
      sl0 = *(const s16x8*)(ApL + k0+32);
      sl1 = *(const s16x8*)(ApL + k0+40);
    }
    s16x8 bh[4], bl[4];
    #pragma unroll
    for (int ni=0;ni<4;ni++){
      size_t boff = (size_t)(bn + wn*64 + ni*16 + lrow)*K + k0 + lk;
      bh[ni] = *(const s16x8*)(Bh + boff);
      bl[ni] = *(const s16x8*)(Bl + boff);
    }
    s16x8 ah[4], al[4];
    #pragma unroll
    for (int mi=0;mi<4;mi++){
      ah[mi] = *(s16x8*)&Ah_s[wm*64 + mi*16 + lrow][lk];
      al[mi] = *(s16x8*)&Al_s[wm*64 + mi*16 + lrow][lk];
    }
    #pragma unroll
    for (int ni=0;ni<4;ni++){
      #pragma unroll
      for (int mi=0;mi<4;mi++){
        acc[mi][ni] = __builtin_amdgcn_mfma_f32_16x16x32_bf16(ah[mi], bh[ni], acc[mi][ni], 0,0,0);
        acc[mi][ni] = __builtin_amdgcn_mfma_f32_16x16x32_bf16(ah[mi], bl[ni], acc[mi][ni], 0,0,0);
        acc[mi][ni] = __builtin_amdgcn_mfma_f32_16x16x32_bf16(al[mi], bh[ni], acc[mi][ni], 0,0,0);
      }
    }
    __syncthreads();
  }
  #pragma unroll
  for (int mi=0;mi<4;mi++)
    #pragma unroll
    for (int ni=0;ni<4;ni++){
      #pragma unroll
      for (int j=0;j<4;j++){
        int m = bm + wm*64 + mi*16 + (wl>>4)*4 + j;
        int n = bn + wn*64 + ni*16 + (wl&15);
        float v = acc[mi][ni][j] + (bias ? bias[n] : 0.f);
        epi(m, n, v);
      }
    }
}

// ---------------- concatenated 3-GEMM launch (shared A planes, per-sub B/K/offset) ---
struct SubDesc {
  const unsigned short* Bh; const unsigned short* Bl;
  const float* bias;
  int K; int aOff; int xTiles; int vbase;
};
struct Cat3 { SubDesc s[3]; };

// MODE 1: phase-1 epilogue (vcol<576 -> xextra fp32; else split -> msg planes)
// MODE 3: phase-3 epilogue (val = v*alpha[head], fp32, chunk-local m)
template<int MODE>
__global__ __launch_bounds__(256) void gemmCat(const unsigned short* __restrict__ Ah,
    const unsigned short* __restrict__ Al, int sA, Cat3 cat,
    float* __restrict__ xextra, unsigned short* __restrict__ mH, unsigned short* __restrict__ mL,
    float* __restrict__ val, const float* __restrict__ alpha, int e0)
{
  __shared__ unsigned short Ah_s[128][40];
  __shared__ unsigned short Al_s[128][40];
  int bx = blockIdx.x, si = 0;
  while (bx >= cat.s[si].xTiles){ bx -= cat.s[si].xTiles; si++; }
  const SubDesc S = cat.s[si];
  const int K = S.K;
  int tid = threadIdx.x;
  int bm = blockIdx.y*128, bn = bx*128;
  int wl = tid & 63, wid = tid >> 6;
  int wm = wid >> 1, wn = wid & 1;
  int lrow = wl & 15, lk = (wl >> 4) * 8;
  int srow = tid >> 1, scolb = (tid & 1) * 16;
  const unsigned short* ApH = Ah + S.aOff + (size_t)(bm + srow)*sA + scolb;
  const unsigned short* ApL = Al + S.aOff + (size_t)(bm + srow)*sA + scolb;

  f32x4 acc[4][4];
  #pragma unroll
  for (int i=0;i<4;i++)
    #pragma unroll
    for (int j=0;j<4;j++){ f32x4 z = {0.f,0.f,0.f,0.f}; acc[i][j] = z; }

  s16x8 sh0 = *(const s16x8*)(ApH);
  s16x8 sh1 = *(const s16x8*)(ApH + 8);
  s16x8 sl0 = *(const s16x8*)(ApL);
  s16x8 sl1 = *(const s16x8*)(ApL + 8);

  for (int k0 = 0; k0 < K; k0 += 32){
    *(s16x8*)&Ah_s[srow][scolb]   = sh0;
    *(s16x8*)&Ah_s[srow][scolb+8] = sh1;
    *(s16x8*)&Al_s[srow][scolb]   = sl0;
    *(s16x8*)&Al_s[srow][scolb+8] = sl1;
    __syncthreads();
    if (k0 + 32 < K){
      sh0 = *(const s16x8*)(ApH + k0+32);
      sh1 = *(const s16x8*)(ApH + k0+40);
      sl0 = *(const s16x8*)(ApL + k0+32);
      sl1 = *(const s16x8*)(ApL + k0+40);
    }
    s16x8 bh[4], bl[4];
    #pragma unroll
    for (int ni=0;ni<4;ni++){
      size_t boff = (size_t)(bn + wn*64 + ni*16 + lrow)*K + k0 + lk;
      bh[ni] = *(const s16x8*)(S.Bh + boff);
      bl[ni] = *(const s16x8*)(S.Bl + boff);
    }
    s16x8 ah[4], al[4];
    #pragma unroll
    for (int mi=0;mi<4;mi++){
      ah[mi] = *(s16x8*)&Ah_s[wm*64 + mi*16 + lrow][lk];
      al[mi] = *(s16x8*)&Al_s[wm*64 + mi*16 + lrow][lk];
    }
    #pragma unroll
    for (int ni=0;ni<4;ni++){
      #pragma unroll
      for (int mi=0;mi<4;mi++){
        acc[mi][ni] = __builtin_amdgcn_mfma_f32_16x16x32_bf16(ah[mi], bh[ni], acc[mi][ni], 0,0,0);
        acc[mi][ni] = __builtin_amdgcn_mfma_f32_16x16x32_bf16(ah[mi], bl[ni], acc[mi][ni], 0,0,0);
        acc[mi][ni] = __builtin_amdgcn_mfma_f32_16x16x32_bf16(al[mi], bh[ni], acc[mi][ni], 0,0,0);
      }
    }
    __syncthreads();
  }
  #pragma unroll
  for (int mi=0;mi<4;mi++)
    #pragma unroll
    for (int ni=0;ni<4;ni++){
      #pragma unroll
      for (int j=0;j<4;j++){
        int m = bm + wm*64 + mi*16 + (wl>>4)*4 + j;
        int n = bn + wn*64 + ni*16 + (wl&15);
        float v = acc[mi][ni][j] + (S.bias ? S.bias[n] : 0.f);
        int vcol = S.vbase + n;
        if (MODE == 1){
          int e = e0 + m;
          if (vcol < EXTRA_) xextra[(size_t)e*EXTRA_ + vcol] = v;
          else {
            unsigned short hh, ll; bfsplit(v, hh, ll);
            mH[(size_t)e*MSGW + vcol - EXTRA_] = hh;
            mL[(size_t)e*MSGW + vcol - EXTRA_] = ll;
          }
        } else {
          int head = (vcol & 127) >> 4;
          float a = alpha[(size_t)(e0+m)*NHEAD + head];
          val[(size_t)m*VALW + vcol] = v*a;
        }
      }
    }
}

// ---------------- attention: LN + gate + logit ----------------
__global__ __launch_bounds__(64) void k_alpha(const float* __restrict__ xextra,
    const float* __restrict__ ag, const float* __restrict__ ab,
    const float* __restrict__ adot, float* __restrict__ logit)
{
  int e = blockIdx.x; int t = threadIdx.x;
  float gv = ag[t], bv = ab[t];
  #pragma unroll
  for (int h=0; h<NHEAD; h++){
    float xv = xextra[(size_t)e*EXTRA_ + h*ACH + t];
    float s1 = waveSum64(xv), s2 = waveSum64(xv*xv);
    float mu = s1*(1.f/64.f), var = s2*(1.f/64.f)-mu*mu;
    float a = (xv-mu)*rsqrtf(var+1e-5f)*gv + bv;
    float sg = 1.f/(1.f+__expf(-a));
    float a2 = 0.6f*a + 0.4f*a*(2.f*sg-1.f);
    float p = a2 * adot[h*ACH + t];
    float ps = waveSum64(p);
    if (t==0) logit[(size_t)e*NHEAD + h] = ps;
  }
}
__global__ __launch_bounds__(64) void k_softmax(const int* __restrict__ coff, const int* __restrict__ cedges,
    const float* __restrict__ logit, float* __restrict__ alpha)
{
  int node = blockIdx.x; int t = threadIdx.x;
  int s = coff[node], en = coff[node+1];
  if (t < NHEAD){
    float m = -1e30f;
    for (int i=s;i<en;i++){ int e = cedges[i]; m = fmaxf(m, logit[(size_t)e*NHEAD+t]); }
    float den = 0.f;
    for (int i=s;i<en;i++){ int e = cedges[i]; den += __expf(logit[(size_t)e*NHEAD+t]-m); }
    den += 1e-16f;
    for (int i=s;i<en;i++){ int e = cedges[i];
      alpha[(size_t)e*NHEAD+t] = __expf(logit[(size_t)e*NHEAD+t]-m)/den; }
  }
}

// ---------------- grid act: 4 edges/block, in-place on split msg planes -------------
__global__ __launch_bounds__(256) void k_grid(unsigned short* __restrict__ msgH,
      unsigned short* __restrict__ msgL, const float* __restrict__ xextra,
      const float* __restrict__ tgp, const float* __restrict__ fgp)
{
  int e = blockIdx.x*4 + (threadIdx.x>>6); int c = threadIdx.x & 63;
  size_t base = (size_t)e*MSGW;
  float msg[MRED], tens[MRED];
  #pragma unroll
  for (int k=0;k<MRED;k++){
    msg[k] = bfjoin(msgH[base + k*HH + c], msgL[base + k*HH + c]);
    tens[k] = 0.f;
  }
  for (int ba=0; ba<RESBA; ba++){
    const float* tg = tgp + ba*MRED;
    const float* fg = fgp + ba*MRED;
    float g = 0.f;
    #pragma unroll
    for (int k=0;k<MRED;k++) g = fmaf(tg[k], msg[k], g);
    g = silu_(g);
    #pragma unroll
    for (int k=1;k<MRED;k++) tens[k] = fmaf(fg[k], g, tens[k]);
  }
  unsigned short hh, ll;
  float r0 = silu_(xextra[(size_t)e*EXTRA_ + ALPHACH_ + c]);
  bfsplit(r0, hh, ll);
  msgH[base + c] = hh; msgL[base + c] = ll;
  #pragma unroll
  for (int k=1;k<MRED;k++){
    bfsplit(tens[k], hh, ll);
    msgH[base + k*HH + c] = hh;
    msgL[base + k*HH + c] = ll;
  }
}

// ---------------- wigner^T scatter into node (per chunk, CSR-owned rows) -----------
__global__ __launch_bounds__(128) void k_scatter(const int* __restrict__ coff, const int* __restrict__ cedges,
      const float* __restrict__ wig, const float* __restrict__ valc, float* __restrict__ node,
      int e0, int e1)
{
  int nd = blockIdx.x; int c = threadIdx.x;
  int s = coff[nd], en = coff[nd+1];
  float acc[NCOEF];
  #pragma unroll
  for (int q=0;q<NCOEF;q++) acc[q]=0.f;
  bool any=false;
  for (int i=s;i<en;i++){
    int e = cedges[i];
    if (e < e0 || e >= e1) continue;
    any = true;
    const float* vb = valc + (size_t)(e-e0)*VALW + c;
    float v[MRED];
    #pragma unroll
    for (int r=0;r<MRED;r++) v[r] = vb[r*128];
    const float* wb = wig + (size_t)e*MRED*NCOEF;
    #pragma unroll
    for (int r=0;r<MRED;r++){
      const float* wr = wb + PERM_M_c[r]*NCOEF;
      #pragma unroll
      for (int q=0;q<NCOEF;q++) acc[q] = fmaf(wr[q], v[r], acc[q]);
    }
  }
  if (any){
    float* nb = node + (size_t)nd*NCOEF*128 + c;
    #pragma unroll
    for (int q=0;q<NCOEF;q++) nb[q*128] += acc[q];
  }
}

// ---------------- final projection (pwt pre-transposed [l][v][o]) ----------------
__global__ __launch_bounds__(128) void k_proj(const float* __restrict__ node, const float* __restrict__ pwt,
      const float* __restrict__ pb, float* __restrict__ out)
{
  int b = blockIdx.x, l = blockIdx.y;
  int o = threadIdx.x;
  int i0 = l*l; int nrow = 2*l+1;
  __shared__ float ns[13][128];
  for (int r=0;r<nrow;r++) ns[r][o] = node[((size_t)b*NCOEF + i0 + r)*128 + o];
  __syncthreads();
  float acc[13];
  #pragma unroll
  for (int r=0;r<13;r++) acc[r] = (i0+r==0) ? pb[o] : 0.f;
  const float* pw = pwt + (size_t)l*16384 + o;
  for (int v=0;v<128;v++){
    float w = pw[v*128];
    #pragma unroll
    for (int r=0;r<13;r++) if (r<nrow) acc[r] = fmaf(ns[r][v], w, acc[r]);
  }
  #pragma unroll
  for (int r=0;r<13;r++) if (r<nrow) out[((size_t)b*NCOEF + i0 + r)*128 + o] = acc[r];
}

// =======================================================================================
static inline size_t al256(size_t x){ return (x+255)&~(size_t)255; }

extern "C" void kernel_launch(void* const* d_in, const int* in_sizes, int n_in,
                              void* d_out, int out_size, void* d_ws, size_t ws_size,
                              hipStream_t stream) {
  const float* x     = (const float*)d_in[0];
  const int*   an    = (const int*)  d_in[1];
  const float* ed    = (const float*)d_in[2];
  const int*   ei    = (const int*)  d_in[3];
  const float* semb  = (const float*)d_in[4];
  const float* temb  = (const float*)d_in[5];
  const float* w1    = (const float*)d_in[6];
  const float* b1    = (const float*)d_in[7];
  const float* g1    = (const float*)d_in[8];
  const float* bt1   = (const float*)d_in[9];
  const float* w2    = (const float*)d_in[10];
  const float* b2    = (const float*)d_in[11];
  const float* g2    = (const float*)d_in[12];
  const float* bt2   = (const float*)d_in[13];
  const float* w3    = (const float*)d_in[14];
  const float* b3    = (const float*)d_in[15];
  const float* wig   = (const float*)d_in[16];
  const float* c1m0w = (const float*)d_in[17];
  const float* c1m0b = (const float*)d_in[18];
  const float* c1m1w = (const float*)d_in[19];
  const float* c1m2w = (const float*)d_in[20];
  const float* ag    = (const float*)d_in[21];
  const float* abv   = (const float*)d_in[22];
  const float* adot  = (const float*)d_in[23];
  const float* tg    = (const float*)d_in[24];
  const float* fg    = (const float*)d_in[25];
  const float* c2m0w = (const float*)d_in[26];
  const float* c2m0b = (const float*)d_in[27];
  const float* c2m1w = (const float*)d_in[28];
  const float* c2m2w = (const float*)d_in[29];
  const float* pw    = (const float*)d_in[30];
  const float* pb    = (const float*)d_in[31];
  float* out = (float*)d_out;

  char* base = (char*)d_ws;
  size_t off = 0;
  auto allocf = [&](size_t n)->float* { float* p = (float*)(base+off); off += al256(n*sizeof(float)); return p; };
  auto allocu = [&](size_t n)->unsigned short* { unsigned short* p = (unsigned short*)(base+off); off += al256(n*2); return p; };
  const size_t n1e = (size_t)768*3072, n2e = (size_t)640*2560, n3e = (size_t)1536*768,
               n4e = (size_t)1280*640, g1e = (size_t)1024*1792, v0e = (size_t)896*448,
               rre = (size_t)4608*128;
  unsigned short* Wt1h = allocu(n1e); unsigned short* Wt1l = allocu(n1e);
  unsigned short* Wt2h = allocu(n2e); unsigned short* Wt2l = allocu(n2e);
  unsigned short* Wt3h = allocu(n3e); unsigned short* Wt3l = allocu(n3e);
  unsigned short* Wt4h = allocu(n4e); unsigned short* Wt4l = allocu(n4e);
  unsigned short* Wg1h = allocu(g1e); unsigned short* Wg1l = allocu(g1e);
  unsigned short* Wv0h = allocu(v0e); unsigned short* Wv0l = allocu(v0e);
  unsigned short* Wrh  = allocu(rre); unsigned short* Wrl  = allocu(rre);
  unsigned short* h2H  = allocu((size_t)E_*ECHN);
  unsigned short* h2L  = allocu((size_t)E_*ECHN);
  unsigned short* msgH = allocu((size_t)E_*MSGW);
  unsigned short* msgL = allocu((size_t)E_*MSGW);
  float* tgp    = allocf(RESBA*MRED);
  float* fgp    = allocf(RESBA*MRED);
  float* pwt    = allocf((size_t)7*128*128);
  float* xextra = allocf((size_t)E_*EXTRA_);
  float* logit  = allocf((size_t)E_*NHEAD);
  float* alphab = allocf((size_t)E_*NHEAD);
  int* csr_cnt   = (int*)allocf(NNODE);
  int* csr_off   = (int*)allocf(NNODE+1);
  int* csr_pos   = (int*)allocf(NNODE);
  int* csr_edges = (int*)allocf(E_);
  float* nodeb  = allocf((size_t)NNODE*NCOEF*128);
  size_t fixed_end = off;

  // chunk size: phase-1 temps (rad fp32 + Amm bf16 pair) union with phase-3 val fp32
  int CH = 2048;
  for (;;){
    size_t radb = al256((size_t)CH*RADTOT*4);
    size_t ammb = 2*al256((size_t)CH*AMMW*2);
    size_t valb = al256((size_t)CH*VALW*4);
    size_t big = radb+ammb; if (valb > big) big = valb;
    if (fixed_end + big <= ws_size || CH == 256) break;
    CH >>= 1;
  }
  float* rad_c = (float*)(base + fixed_end);
  unsigned short* AmmH = (unsigned short*)(base + fixed_end + al256((size_t)CH*RADTOT*4));
  unsigned short* AmmL = (unsigned short*)(base + fixed_end + al256((size_t)CH*RADTOT*4) + al256((size_t)CH*AMMW*2));
  float* val_c = (float*)(base + fixed_end);   // aliases rad_c (disjoint phases)

  // ---- prep: grid tables, weight split/transpose, CSR, radial ----
  k_gridtab<<<512, 256, 0, stream>>>(tg, fg, pw, tgp, fgp, pwt);
  k_wsplit_so2<<<2048, 256, 0, stream>>>(c1m1w, Wt1h, Wt1l, 768, 3072, 1536, 384);
  k_wsplit_so2<<<2048, 256, 0, stream>>>(c1m2w, Wt2h, Wt2l, 640, 2560, 1280, 320);
  k_wsplit_so2<<<1024, 256, 0, stream>>>(c2m1w, Wt3h, Wt3l, 1536, 768, 384, 768);
  k_wsplit_so2<<<1024, 256, 0, stream>>>(c2m2w, Wt4h, Wt4l, 1280, 640, 320, 640);
  k_wsplit_plain<<<2048, 256, 0, stream>>>(c1m0w, Wg1h, Wg1l, 1024, 1792);
  k_wsplit_plain<<<512, 256, 0, stream>>>(c2m0w, Wv0h, Wv0l, 896, 448);
  k_wsplit_plain<<<512, 256, 0, stream>>>(w3, Wrh, Wrl, RADTOT, ECHN);
  hipMemsetAsync(csr_cnt, 0, NNODE*sizeof(int), stream);
  k_csr_count<<<E_/256, 256, 0, stream>>>(ei, csr_cnt);
  k_csr_scan<<<1, NNODE, 0, stream>>>(csr_cnt, csr_off, csr_pos);
  k_csr_fill<<<E_/256, 256, 0, stream>>>(ei, csr_pos, csr_edges);
  k_radial<<<E_/EPB, 128, 0, stream>>>(ed, an, ei, semb, temb,
                                       w1, b1, g1, bt1, w2, b2, g2, bt2, h2H, h2L);

  // descriptor tables
  Cat3 catP1;
  catP1.s[0] = SubDesc{Wg1h, Wg1l, c1m0b, 1792, 0,    8, 0};
  catP1.s[1] = SubDesc{Wt1h, Wt1l, nullptr, 3072, 1792, 6, 1024};
  catP1.s[2] = SubDesc{Wt2h, Wt2l, nullptr, 2560, 4864, 5, 1792};
  Cat3 catP3;
  catP3.s[0] = SubDesc{Wv0h, Wv0l, c2m0b, 448,  0,    7, 0};
  catP3.s[1] = SubDesc{Wt3h, Wt3l, nullptr, 768,  448,  12, 896};
  catP3.s[2] = SubDesc{Wt4h, Wt4l, nullptr, 640,  1216, 10, 2432};

  // ---- phase 1: per chunk: rad GEMM, wigner-rotate(split), merged SO2 conv #1 ----
  for (int e0 = 0; e0 < E_; e0 += CH){
    gemmMF<EpiRad><<<dim3(RADTOT/128, CH/128), 256, 0, stream>>>(
        h2H + (size_t)e0*ECHN, h2L + (size_t)e0*ECHN, ECHN, Wrh, Wrl, RADTOT, ECHN, b3, EpiRad{rad_c});
    k_wigmm<<<CH, 256, 0, stream>>>(x, ei, wig, rad_c, AmmH, AmmL, e0);
    gemmCat<1><<<dim3(19, CH/128), 256, 0, stream>>>(
        AmmH, AmmL, AMMW, catP1, xextra, msgH, msgL, nullptr, nullptr, e0);
  }

  // ---- phase 2: attention softmax + grid activation (in-place on msg planes) ----
  k_alpha<<<E_, 64, 0, stream>>>(xextra, ag, abv, adot, logit);
  k_softmax<<<NNODE, 64, 0, stream>>>(csr_off, csr_edges, logit, alphab);
  k_grid<<<E_/4, 256, 0, stream>>>(msgH, msgL, xextra, tgp, fgp);

  // ---- phase 3+4: per chunk: merged SO2 conv #2 (alpha-scaled) + wigner^T scatter ----
  hipMemsetAsync(nodeb, 0, (size_t)NNODE*NCOEF*128*sizeof(float), stream);
  for (int e0 = 0; e0 < E_; e0 += CH){
    gemmCat<3><<<dim3(29, CH/128), 256, 0, stream>>>(
        msgH + (size_t)e0*MSGW, msgL + (size_t)e0*MSGW, MSGW, catP3,
        nullptr, nullptr, nullptr, val_c, alphab, e0);
    k_scatter<<<NNODE, 128, 0, stream>>>(csr_off, csr_edges, wig, val_c, nodeb, e0, e0+CH);
  }

  // ---- phase 5: projection ----
  k_proj<<<dim3(NNODE, 7), 128, 0, stream>>>(nodeb, pwt, pb, out);
}